// Round 2
// baseline (212.672 us; speedup 1.0000x reference)
//
#include <hip/hip_runtime.h>
#include <hip/hip_bf16.h>
#include <stdint.h>

typedef unsigned short ushort_t;
using short8   = __attribute__((ext_vector_type(8))) short;
using float4v  = __attribute__((ext_vector_type(4))) float;
using uint4v   = __attribute__((ext_vector_type(4))) unsigned;

#define BSH    6          // bucket = 64 consecutive dst nodes
#define BUCKW  64
#define CAP    1536       // per-bucket capacity (avg 1024, +16 sigma)
#define NBMAX  2048
#define BINB   256        // binning blocks (1024 thr each)
#define HPITCH 136
#define APITCH 36         // agg_s pitch in dwords: 144B rows, 16B-aligned, 2-way banks

__device__ __forceinline__ float bf2f(ushort_t u) {
    union { unsigned int i; float f; } v;
    v.i = ((unsigned int)u) << 16;
    return v.f;
}
__device__ __forceinline__ ushort_t f2b(float f) {
    union { float f; unsigned int i; } v;
    v.f = f;
    unsigned int u = v.i;
    unsigned int r = (u + 0x7fffu + ((u >> 16) & 1u)) >> 16;   // RNE
    return (ushort_t)r;
}
__device__ __forceinline__ float blo2f(unsigned v) {   // low bf16 of dword
    union { unsigned i; float f; } u; u.i = v << 16; return u.f;
}
__device__ __forceinline__ float bhi2f(unsigned v) {   // high bf16 of dword
    union { unsigned i; float f; } u; u.i = v & 0xFFFF0000u; return u.f;
}

// ---------------------------------------------------------------------------
// prep_k: heterogeneous roles, 1024 threads. BINNING FIRST (blocks 0..BINB-1)
// so the long-pole role starts at t=0 and runs at 256 blocks x 16 waves
// (50% occupancy cap) instead of round-1's 25%.
//  binning: two-sweep block-private counting sort; int4-batched dst/src reads
//           (4x fewer VMEM instrs). gcur pre-zeroed; bases bucket-relative.
//  transpose: register-direct, 256 nodes/block, 16 strided loads per thread,
//           2x16B stores (sibling dim-blocks fill lines -> L2 merge).
// ---------------------------------------------------------------------------
__global__ __launch_bounds__(1024) void prep_k(
        const float* __restrict__ inp, ushort_t* __restrict__ X, int N,
        const float* __restrict__ W1, const float* __restrict__ W2,
        ushort_t* __restrict__ w1b, ushort_t* __restrict__ w2b,
        const int* __restrict__ src, const int* __restrict__ dst,
        int* __restrict__ gcur, unsigned* __restrict__ bin, int E,
        int NB) {
    __shared__ int lcnt[NBMAX];
    __shared__ int gbase[NBMAX];
    __shared__ int lcur[NBMAX];
    int tid = threadIdx.x;

    if ((int)blockIdx.x >= BINB) {
        // ---------------- transpose role (register-direct) ----------------
        int tb = blockIdx.x - BINB;
        if (tb == 0) {
            for (int i = tid; i < 8192; i += 1024) {
                w1b[i] = f2b(W1[i]);
                w2b[i] = f2b(W2[i]);
            }
        }
        int db = tid >> 8;                  // 0..3: 16-dim block
        int nl = tid & 255;                 // node within tile
        int nc = tb * 256 + nl;
        if (nc < N) {
            unsigned ib = (unsigned)(db * 16) * (unsigned)N + (unsigned)nc;
            float v[16];
#pragma unroll
            for (int r = 0; r < 16; ++r)    // 16 independent strided loads
                v[r] = inp[ib + (unsigned)(r * N)];
            unsigned dw[8];
#pragma unroll
            for (int j = 0; j < 8; ++j)
                dw[j] = (unsigned)f2b(v[2 * j]) | ((unsigned)f2b(v[2 * j + 1]) << 16);
            unsigned* xp = (unsigned*)X + (((unsigned)nc) << 5) + (unsigned)(db << 3);
            uint4v a = {dw[0], dw[1], dw[2], dw[3]};
            uint4v b = {dw[4], dw[5], dw[6], dw[7]};
            *(uint4v*)(xp)     = a;
            *(uint4v*)(xp + 4) = b;
        }
    } else {
        // ---------------- binning role ----------------
        int bid  = blockIdx.x;
        int Q    = (E + 3) >> 2;            // int4 count
        int chunk = (Q + BINB - 1) / BINB;
        int q0 = bid * chunk;
        int q1 = q0 + chunk;
        if (q1 > Q) q1 = Q;
        const int4* dst4 = (const int4*)dst;
        const int4* src4 = (const int4*)src;

        for (int b = tid; b < NB; b += 1024) lcnt[b] = 0;
        __syncthreads();

        // sweep 1: histogram, int4 loads
        for (int q = q0 + tid; q < q1; q += 1024) {
            int e = q << 2;
            if (e + 3 < E) {
                int4 d = dst4[q];
                atomicAdd(&lcnt[d.x >> BSH], 1);
                atomicAdd(&lcnt[d.y >> BSH], 1);
                atomicAdd(&lcnt[d.z >> BSH], 1);
                atomicAdd(&lcnt[d.w >> BSH], 1);
            } else {
                for (int k = e; k < E; ++k) atomicAdd(&lcnt[dst[k] >> BSH], 1);
            }
        }
        __syncthreads();

        for (int b = tid; b < NB; b += 1024) {
            int c = lcnt[b];
            gbase[b] = c ? atomicAdd(&gcur[b], c) : 0;   // relative base
            lcur[b]  = 0;
        }
        __syncthreads();

        // sweep 2: placement, int4 loads
        for (int q = q0 + tid; q < q1; q += 1024) {
            int e = q << 2;
            if (e + 3 < E) {
                int4 d = dst4[q];
                int4 s = src4[q];
                int dv[4] = {d.x, d.y, d.z, d.w};
                int sv[4] = {s.x, s.y, s.z, s.w};
#pragma unroll
                for (int k = 0; k < 4; ++k) {
                    int b   = dv[k] >> BSH;
                    int pos = gbase[b] + atomicAdd(&lcur[b], 1);
                    if (pos < CAP)
                        bin[(size_t)b * CAP + pos] =
                            ((unsigned)(dv[k] & (BUCKW - 1)) << 24) | (unsigned)sv[k];
                }
            } else {
                for (int k = e; k < E; ++k) {
                    int dv = dst[k];
                    int b  = dv >> BSH;
                    int pos = gbase[b] + atomicAdd(&lcur[b], 1);
                    if (pos < CAP)
                        bin[(size_t)b * CAP + pos] =
                            ((unsigned)(dv & (BUCKW - 1)) << 24) | (unsigned)src[k];
                }
            }
        }
    }
}

// ---------------------------------------------------------------------------
// bam_k: FUSED bucket-aggregation + 2-layer MLP. One block = one 64-node
// bucket (same unit as old bagg_k and mlp_k). agg stays in LDS (agg_s,
// pitch 36 dwords = 16B-aligned rows, 2-way bank pattern for ds_read_b128),
// eliminating the 25.6 MB aggb round-trip and one launch.
// sl/ecnt/sc/ecur are dead after the gather barrier, so h_s unions over
// them (pool): LDS total 26.6 KB -> ~5 blocks/CU.
// Gather: counting-sort by local node, DWORD-PAIR mapping (2 edges/load),
// 32-bit saddr offsets ((src<<5)|c2) to cut 64-bit per-lane address VALU.
// ---------------------------------------------------------------------------
__global__ __launch_bounds__(256, 5) void bam_k(
        const unsigned* __restrict__ Xu, const unsigned* __restrict__ bin,
        const int* __restrict__ gcur,
        const ushort_t* __restrict__ W1, const float* __restrict__ b1,
        const ushort_t* __restrict__ W2, const float* __restrict__ b2,
        float* __restrict__ out, int N) {
    __shared__ unsigned agg_s[BUCKW * APITCH];                // 9216 B
    __shared__ __align__(16) char pool[4 * 16 * HPITCH * 2];  // 17408 B
    unsigned* sl  = (unsigned*)pool;                          // [CAP] 6144 B
    int* ecnt = (int*)(pool + CAP * 4);
    int* sc   = ecnt + BUCKW;
    int* ecur = sc + BUCKW;

    int tid = threadIdx.x;
    int b   = blockIdx.x;

    int cnt = gcur[b];
    if (cnt > CAP) cnt = CAP;
    const unsigned* bb = bin + (size_t)b * CAP;

    if (tid < BUCKW) ecnt[tid] = 0;
    __syncthreads();

    for (int i = tid; i < cnt; i += 256)
        atomicAdd(&ecnt[bb[i] >> 24], 1);
    __syncthreads();

    if (tid < BUCKW) sc[tid] = ecnt[tid];
    __syncthreads();
#pragma unroll
    for (int off = 1; off < BUCKW; off <<= 1) {
        int v = 0;
        if (tid < BUCKW && tid >= off) v = sc[tid - off];
        __syncthreads();
        if (tid < BUCKW) sc[tid] += v;
        __syncthreads();
    }
    if (tid < BUCKW) { sc[tid] -= ecnt[tid]; ecur[tid] = 0; }   // exclusive
    __syncthreads();

    for (int i = tid; i < cnt; i += 256) {
        unsigned p = bb[i];
        int nl  = (int)(p >> 24);
        int pos = sc[nl] + atomicAdd(&ecur[nl], 1);
        sl[pos] = p;
    }
    __syncthreads();

    int wave = tid >> 6;               // 0..3
    int lane = tid & 63;
    int half = lane >> 5;              // 0: even edges, 1: odd edges
    unsigned cu = (unsigned)(lane & 31);   // dword index within row

    for (int n = wave; n < BUCKW; n += 4) {
        int s0 = sc[n];
        int c  = ecnt[n];              // 0 for out-of-range nodes -> zeros
        float alo0 = 0.f, ahi0 = 0.f, alo1 = 0.f, ahi1 = 0.f;
        int i = 0;
        for (; i + 16 <= c; i += 16) {
            unsigned p0 = sl[s0 + i +  0 + half], p1 = sl[s0 + i +  2 + half];
            unsigned p2 = sl[s0 + i +  4 + half], p3 = sl[s0 + i +  6 + half];
            unsigned p4 = sl[s0 + i +  8 + half], p5 = sl[s0 + i + 10 + half];
            unsigned p6 = sl[s0 + i + 12 + half], p7 = sl[s0 + i + 14 + half];
            unsigned v0 = Xu[((p0 & 0xFFFFFFu) << 5) | cu];
            unsigned v1 = Xu[((p1 & 0xFFFFFFu) << 5) | cu];
            unsigned v2 = Xu[((p2 & 0xFFFFFFu) << 5) | cu];
            unsigned v3 = Xu[((p3 & 0xFFFFFFu) << 5) | cu];
            unsigned v4 = Xu[((p4 & 0xFFFFFFu) << 5) | cu];
            unsigned v5 = Xu[((p5 & 0xFFFFFFu) << 5) | cu];
            unsigned v6 = Xu[((p6 & 0xFFFFFFu) << 5) | cu];
            unsigned v7 = Xu[((p7 & 0xFFFFFFu) << 5) | cu];
            alo0 += blo2f(v0); ahi0 += bhi2f(v0);
            alo1 += blo2f(v1); ahi1 += bhi2f(v1);
            alo0 += blo2f(v2); ahi0 += bhi2f(v2);
            alo1 += blo2f(v3); ahi1 += bhi2f(v3);
            alo0 += blo2f(v4); ahi0 += bhi2f(v4);
            alo1 += blo2f(v5); ahi1 += bhi2f(v5);
            alo0 += blo2f(v6); ahi0 += bhi2f(v6);
            alo1 += blo2f(v7); ahi1 += bhi2f(v7);
        }
        for (; i + 2 <= c; i += 2) {
            unsigned p = sl[s0 + i + half];
            unsigned v = Xu[((p & 0xFFFFFFu) << 5) | cu];
            alo0 += blo2f(v); ahi0 += bhi2f(v);
        }
        if (i + half < c) {            // odd tail
            unsigned p = sl[s0 + i + half];
            unsigned v = Xu[((p & 0xFFFFFFu) << 5) | cu];
            alo1 += blo2f(v); ahi1 += bhi2f(v);
        }
        float alo = alo0 + alo1;
        float ahi = ahi0 + ahi1;
        float blo = __shfl(alo, lane + 32);
        float bhi = __shfl(ahi, lane + 32);
        if (half == 0) {
            alo += blo; ahi += bhi;
            agg_s[n * APITCH + (int)cu] =
                (unsigned)f2b(alo) | ((unsigned)f2b(ahi) << 16);
        }
    }
    __syncthreads();    // agg complete; sl/counters dead -> pool reused as h_s

    // ---------------- fused MLP (frag maps as verified mlp_k) ----------------
    ushort_t* hw = (ushort_t*)pool + (size_t)wave * (16 * HPITCH);
    int row  = lane & 15;
    int quad = lane >> 4;

    const unsigned* arow = agg_s + (wave * 16 + row) * APITCH;
    short8 a0 = *(const short8*)(arow + quad * 4);
    short8 a1 = *(const short8*)(arow + 16 + quad * 4);

    float4v zero = {0.f, 0.f, 0.f, 0.f};

    // layer 1 in two nt-groups of 4 (halves live acc regs: 16 vs 32)
#pragma unroll
    for (int g = 0; g < 2; ++g) {
        float4v acc[4];
#pragma unroll
        for (int nt = 0; nt < 4; ++nt) acc[nt] = zero;
#pragma unroll
        for (int nt = 0; nt < 4; ++nt) {
            const ushort_t* wp = W1 + (size_t)(g * 64 + nt * 16 + row) * 64 + quad * 8;
            short8 bf0 = *(const short8*)(wp);
            short8 bf1 = *(const short8*)(wp + 32);
            acc[nt] = __builtin_amdgcn_mfma_f32_16x16x32_bf16(a0, bf0, acc[nt], 0, 0, 0);
            acc[nt] = __builtin_amdgcn_mfma_f32_16x16x32_bf16(a1, bf1, acc[nt], 0, 0, 0);
        }
#pragma unroll
        for (int nt = 0; nt < 4; ++nt) {
            float bias = b1[g * 64 + nt * 16 + row];
#pragma unroll
            for (int r = 0; r < 4; ++r) {
                float v = acc[nt][r] + bias;
                v = v > 0.f ? v : 0.f;
                hw[(quad * 4 + r) * HPITCH + g * 64 + nt * 16 + row] = f2b(v);
            }
        }
    }
    __syncthreads();

    short8 a2[4];
#pragma unroll
    for (int kt = 0; kt < 4; ++kt)
        a2[kt] = *(const short8*)(hw + row * HPITCH + kt * 32 + quad * 8);

    float4v acc2[4];
#pragma unroll
    for (int nt = 0; nt < 4; ++nt) acc2[nt] = zero;

#pragma unroll
    for (int nt = 0; nt < 4; ++nt) {
#pragma unroll
        for (int kt = 0; kt < 4; ++kt) {
            short8 bfr = *(const short8*)(W2 + (size_t)(nt * 16 + row) * 128 +
                                          kt * 32 + quad * 8);
            acc2[nt] = __builtin_amdgcn_mfma_f32_16x16x32_bf16(a2[kt], bfr, acc2[nt], 0, 0, 0);
        }
    }

    int n0   = (b << BSH) + wave * 16;
    int node = n0 + quad * 4;
#pragma unroll
    for (int nt = 0; nt < 4; ++nt) {
        int ko = nt * 16 + row;
        float bias = b2[ko];
        float4v pk;
#pragma unroll
        for (int r = 0; r < 4; ++r) pk[r] = acc2[nt][r] + bias;
        if (node + 3 < N) {
            *(float4v*)(out + (size_t)ko * N + node) = pk;
        } else {
#pragma unroll
            for (int r = 0; r < 4; ++r)
                if (node + r < N) out[(size_t)ko * N + node + r] = pk[r];
        }
    }
}

// ---------------------------------------------------------------------------
// Fallback pair (small-ws path): verified bagg_k + mlp_k from round 1,
// gather addressing upgraded to 32-bit offsets.
// ---------------------------------------------------------------------------
__global__ __launch_bounds__(256) void bagg_k(
        const unsigned* __restrict__ Xu, const unsigned* __restrict__ bin,
        const int* __restrict__ gcur, unsigned* __restrict__ aggu, int N) {
    __shared__ unsigned sl[CAP];
    __shared__ int ecnt[BUCKW];
    __shared__ int sc[BUCKW];
    __shared__ int ecur[BUCKW];
    int tid = threadIdx.x;
    int b   = blockIdx.x;
    int lo  = b << BSH;

    int cnt = gcur[b];
    if (cnt > CAP) cnt = CAP;
    const unsigned* bb = bin + (size_t)b * CAP;

    if (tid < BUCKW) ecnt[tid] = 0;
    __syncthreads();
    for (int i = tid; i < cnt; i += 256)
        atomicAdd(&ecnt[bb[i] >> 24], 1);
    __syncthreads();
    if (tid < BUCKW) sc[tid] = ecnt[tid];
    __syncthreads();
#pragma unroll
    for (int off = 1; off < BUCKW; off <<= 1) {
        int v = 0;
        if (tid < BUCKW && tid >= off) v = sc[tid - off];
        __syncthreads();
        if (tid < BUCKW) sc[tid] += v;
        __syncthreads();
    }
    if (tid < BUCKW) { sc[tid] -= ecnt[tid]; ecur[tid] = 0; }
    __syncthreads();
    for (int i = tid; i < cnt; i += 256) {
        unsigned p = bb[i];
        int nl  = (int)(p >> 24);
        int pos = sc[nl] + atomicAdd(&ecur[nl], 1);
        sl[pos] = p;
    }
    __syncthreads();

    int wave = tid >> 6;
    int lane = tid & 63;
    int half = lane >> 5;
    unsigned cu = (unsigned)(lane & 31);

    for (int n = wave; n < BUCKW; n += 4) {
        int node = lo + n;
        if (node >= N) break;
        int s0 = sc[n];
        int c  = ecnt[n];
        float alo0 = 0.f, ahi0 = 0.f, alo1 = 0.f, ahi1 = 0.f;
        int i = 0;
        for (; i + 16 <= c; i += 16) {
            unsigned p0 = sl[s0 + i +  0 + half], p1 = sl[s0 + i +  2 + half];
            unsigned p2 = sl[s0 + i +  4 + half], p3 = sl[s0 + i +  6 + half];
            unsigned p4 = sl[s0 + i +  8 + half], p5 = sl[s0 + i + 10 + half];
            unsigned p6 = sl[s0 + i + 12 + half], p7 = sl[s0 + i + 14 + half];
            unsigned v0 = Xu[((p0 & 0xFFFFFFu) << 5) | cu];
            unsigned v1 = Xu[((p1 & 0xFFFFFFu) << 5) | cu];
            unsigned v2 = Xu[((p2 & 0xFFFFFFu) << 5) | cu];
            unsigned v3 = Xu[((p3 & 0xFFFFFFu) << 5) | cu];
            unsigned v4 = Xu[((p4 & 0xFFFFFFu) << 5) | cu];
            unsigned v5 = Xu[((p5 & 0xFFFFFFu) << 5) | cu];
            unsigned v6 = Xu[((p6 & 0xFFFFFFu) << 5) | cu];
            unsigned v7 = Xu[((p7 & 0xFFFFFFu) << 5) | cu];
            alo0 += blo2f(v0); ahi0 += bhi2f(v0);
            alo1 += blo2f(v1); ahi1 += bhi2f(v1);
            alo0 += blo2f(v2); ahi0 += bhi2f(v2);
            alo1 += blo2f(v3); ahi1 += bhi2f(v3);
            alo0 += blo2f(v4); ahi0 += bhi2f(v4);
            alo1 += blo2f(v5); ahi1 += bhi2f(v5);
            alo0 += blo2f(v6); ahi0 += bhi2f(v6);
            alo1 += blo2f(v7); ahi1 += bhi2f(v7);
        }
        for (; i + 2 <= c; i += 2) {
            unsigned p = sl[s0 + i + half];
            unsigned v = Xu[((p & 0xFFFFFFu) << 5) | cu];
            alo0 += blo2f(v); ahi0 += bhi2f(v);
        }
        if (i + half < c) {
            unsigned p = sl[s0 + i + half];
            unsigned v = Xu[((p & 0xFFFFFFu) << 5) | cu];
            alo1 += blo2f(v); ahi1 += bhi2f(v);
        }
        float alo = alo0 + alo1;
        float ahi = ahi0 + ahi1;
        float blo = __shfl(alo, lane + 32);
        float bhi = __shfl(ahi, lane + 32);
        if (half == 0) {
            alo += blo; ahi += bhi;
            aggu[(size_t)node * 32 + (int)cu] =
                (unsigned)f2b(alo) | ((unsigned)f2b(ahi) << 16);
        }
    }
}

__global__ __launch_bounds__(256) void mlp_k(
        const ushort_t* __restrict__ aggb,
        const ushort_t* __restrict__ W1, const float* __restrict__ b1,
        const ushort_t* __restrict__ W2, const float* __restrict__ b2,
        float* __restrict__ out, int N) {
    __shared__ ushort_t h_s[4][16 * HPITCH];

    int wave = threadIdx.x >> 6;
    int lane = threadIdx.x & 63;
    int row  = lane & 15;
    int quad = lane >> 4;
    int n0   = blockIdx.x * 64 + wave * 16;

    int anode = n0 + row;
    if (anode > N - 1) anode = N - 1;
    const ushort_t* ap = aggb + (size_t)anode * 64;
    short8 a0 = *(const short8*)(ap + quad * 8);
    short8 a1 = *(const short8*)(ap + 32 + quad * 8);

    float4v zero = {0.f, 0.f, 0.f, 0.f};
    float4v acc[8];
#pragma unroll
    for (int nt = 0; nt < 8; ++nt) acc[nt] = zero;

#pragma unroll
    for (int nt = 0; nt < 8; ++nt) {
        const ushort_t* wp = W1 + (size_t)(nt * 16 + row) * 64 + quad * 8;
        short8 bf0 = *(const short8*)(wp);
        short8 bf1 = *(const short8*)(wp + 32);
        acc[nt] = __builtin_amdgcn_mfma_f32_16x16x32_bf16(a0, bf0, acc[nt], 0, 0, 0);
        acc[nt] = __builtin_amdgcn_mfma_f32_16x16x32_bf16(a1, bf1, acc[nt], 0, 0, 0);
    }

    ushort_t* hw = h_s[wave];
#pragma unroll
    for (int nt = 0; nt < 8; ++nt) {
        float bias = b1[nt * 16 + row];
#pragma unroll
        for (int r = 0; r < 4; ++r) {
            float v = acc[nt][r] + bias;
            v = v > 0.f ? v : 0.f;
            hw[(quad * 4 + r) * HPITCH + nt * 16 + row] = f2b(v);
        }
    }
    __syncthreads();

    short8 a2[4];
#pragma unroll
    for (int kt = 0; kt < 4; ++kt)
        a2[kt] = *(const short8*)(hw + row * HPITCH + kt * 32 + quad * 8);

    float4v acc2[4];
#pragma unroll
    for (int nt = 0; nt < 4; ++nt) acc2[nt] = zero;

#pragma unroll
    for (int nt = 0; nt < 4; ++nt) {
#pragma unroll
        for (int kt = 0; kt < 4; ++kt) {
            short8 bfr = *(const short8*)(W2 + (size_t)(nt * 16 + row) * 128 +
                                          kt * 32 + quad * 8);
            acc2[nt] = __builtin_amdgcn_mfma_f32_16x16x32_bf16(a2[kt], bfr, acc2[nt], 0, 0, 0);
        }
    }

    int node = n0 + quad * 4;
    if (node < N) {
#pragma unroll
        for (int nt = 0; nt < 4; ++nt) {
            int ko = nt * 16 + row;
            float bias = b2[ko];
            float4v pk;
#pragma unroll
            for (int r = 0; r < 4; ++r) pk[r] = acc2[nt][r] + bias;
            *(float4v*)(out + (size_t)ko * N + node) = pk;
        }
    }
}

// ---------------------------------------------------------------------------
extern "C" void kernel_launch(void* const* d_in, const int* in_sizes, int n_in,
                              void* d_out, int out_size, void* d_ws, size_t ws_size,
                              hipStream_t stream) {
    const float* inp = (const float*)d_in[0];   // [64][N] fp32
    const int*   src = (const int*)d_in[1];
    const int*   dst = (const int*)d_in[2];
    const float* W1  = (const float*)d_in[3];   // [128][64] fp32
    const float* b1  = (const float*)d_in[4];   // [128] fp32
    const float* W2  = (const float*)d_in[5];   // [64][128] fp32
    const float* b2  = (const float*)d_in[6];   // [64] fp32
    float* out = (float*)d_out;                 // [64][N] fp32

    int N  = in_sizes[0] / 64;
    int E  = in_sizes[1];
    int NB = (N + BUCKW - 1) >> BSH;            // 1563 for N=100000 (<= NBMAX)

    size_t xBytes   = (size_t)N * 64 * 2;       // 12.8 MB
    size_t binBytes = (size_t)NB * CAP * 4;     // 9.6 MB
    size_t fusedNeed = xBytes + binBytes + 2 * 8192 * 2 + NBMAX * 4 + 256;

    int TB = (N + 255) / 256;

    if (ws_size >= fusedNeed) {
        // -------- fused path: X + bin live in ws, out written by bam_k --------
        char* w = (char*)d_ws;
        ushort_t* X    = (ushort_t*)w;
        unsigned* bin  = (unsigned*)(w + xBytes);
        ushort_t* w1b  = (ushort_t*)(w + xBytes + binBytes);
        ushort_t* w2b  = w1b + 8192;
        int*      gcur = (int*)(w2b + 8192);

        hipMemsetAsync(gcur, 0, NB * sizeof(int), stream);

        prep_k<<<BINB + TB, 1024, 0, stream>>>(inp, X, N, W1, W2, w1b, w2b,
                                               src, dst, gcur, bin, E, NB);

        bam_k<<<NB, 256, 0, stream>>>((const unsigned*)X, bin, gcur,
                                      w1b, b1, w2b, b2, out, N);
    } else {
        // -------- fallback: round-1 layout (X+bin staged in d_out) --------
        ushort_t* aggb = (ushort_t*)d_ws;
        ushort_t* w1b  = aggb + (size_t)N * 64;
        ushort_t* w2b  = w1b + 8192;
        int*      gcur = (int*)(w2b + 8192);

        char*     ob  = (char*)d_out;
        ushort_t* X   = (ushort_t*)ob;
        unsigned* bin = (unsigned*)(ob + xBytes);

        hipMemsetAsync(gcur, 0, NB * sizeof(int), stream);

        prep_k<<<BINB + TB, 1024, 0, stream>>>(inp, X, N, W1, W2, w1b, w2b,
                                               src, dst, gcur, bin, E, NB);

        bagg_k<<<NB, 256, 0, stream>>>((const unsigned*)X, bin, gcur,
                                       (unsigned*)aggb, N);

        int tb = (N + 63) / 64;
        mlp_k<<<tb, 256, 0, stream>>>(aggb, w1b, b1, w2b, b2, out, N);
    }
}